// Round 3
// baseline (3170.180 us; speedup 1.0000x reference)
//
#include <hip/hip_runtime.h>

#define N 8192
#define ITERS 50
#define ROWS 8   // rows per block

typedef unsigned int uint32;

// ws layout: [hi plane 128MiB][lo plane 64MiB][bufA N][bufB N][nsq ITERS+1]
// hi plane: ushort bits[31:16] of rounded fp32, row-major
// lo plane: uchar  bits[15:8]  of rounded fp32, row-major

__global__ void pi_init_kernel(float* __restrict__ bufA, float* __restrict__ nsq) {
    int i = blockIdx.x * blockDim.x + threadIdx.x;
    if (i < N) bufA[i] = 1.0f;
    if (i <= ITERS) nsq[i] = (i == 0) ? 1.0f : 0.0f;
}

// shared epilogue: per-row wave reduce -> cross-wave via LDS -> write vout,
// accumulate sum(vout^2) into nsq_next
__device__ __forceinline__ void pi_epilogue(float (&acc)[ROWS], int t, int row0,
                                            float s, float* __restrict__ vout,
                                            float* __restrict__ nsq_next) {
#pragma unroll
    for (int r = 0; r < ROWS; ++r) {
        float a = acc[r];
        for (int off = 32; off > 0; off >>= 1) a += __shfl_down(a, off, 64);
        acc[r] = a;
    }
    __shared__ float part[4][ROWS];
    const int wave = t >> 6, lane = t & 63;
    if (lane == 0) {
#pragma unroll
        for (int r = 0; r < ROWS; ++r) part[wave][r] = acc[r];
    }
    __syncthreads();
    float sq = 0.0f;
    if (t < ROWS) {
        const float sum = part[0][t] + part[1][t] + part[2][t] + part[3][t];
        const float y = sum * s;
        vout[row0 + t] = y;
        sq = y * y;
    }
    if (wave == 0) {
        for (int off = 32; off > 0; off >>= 1) sq += __shfl_down(sq, off, 64);
        if (lane == 0) atomicAdd(nsq_next, sq);
    }
}

// fp32 GEMV (fallback for small ws)
__global__ __launch_bounds__(256) void pi_gemv_kernel(
        const float4* __restrict__ M4,
        const float4* __restrict__ vin4,
        float* __restrict__ vout,
        const float* __restrict__ nsq_prev,
        float* __restrict__ nsq_next) {
    const int t = threadIdx.x;
    const int row0 = blockIdx.x * ROWS;
    const float s = rsqrtf(*nsq_prev);
    constexpr int NV = N / 4;
    constexpr int CHUNKS = NV / 256;
    float acc[ROWS];
#pragma unroll
    for (int r = 0; r < ROWS; ++r) acc[r] = 0.0f;
    for (int c = 0; c < CHUNKS; ++c) {
        const int idx = c * 256 + t;
        const float4 vv = vin4[idx];
#pragma unroll
        for (int r = 0; r < ROWS; ++r) {
            const float4 m = M4[(size_t)(row0 + r) * NV + idx];
            acc[r] += m.x * vv.x + m.y * vv.y + m.z * vv.z + m.w * vv.w;
        }
    }
    pi_epilogue(acc, t, row0, s, vout, nsq_next);
}

// iter 1 fused with conversion to 3-byte planes (round-to-nearest via +0x80)
__global__ __launch_bounds__(256) void pi_gemv_convert_kernel(
        const float4* __restrict__ M4,
        const float4* __restrict__ vin4,
        float* __restrict__ vout,
        const float* __restrict__ nsq_prev,
        float* __restrict__ nsq_next,
        uint2* __restrict__ hi2,     // 1 uint2 per 4 elems, row stride N/4
        uint32* __restrict__ lo1) {  // 1 uint  per 4 elems, row stride N/4
    const int t = threadIdx.x;
    const int row0 = blockIdx.x * ROWS;
    const float s = rsqrtf(*nsq_prev);
    constexpr int NV = N / 4;
    constexpr int CHUNKS = NV / 256;
    float acc[ROWS];
#pragma unroll
    for (int r = 0; r < ROWS; ++r) acc[r] = 0.0f;
    for (int c = 0; c < CHUNKS; ++c) {
        const int idx = c * 256 + t;
        const float4 vv = vin4[idx];
#pragma unroll
        for (int r = 0; r < ROWS; ++r) {
            const size_t off = (size_t)(row0 + r) * NV + idx;
            const float4 m = M4[off];
            acc[r] += m.x * vv.x + m.y * vv.y + m.z * vv.z + m.w * vv.w;
            const uint32 u0 = __float_as_uint(m.x) + 0x80u;
            const uint32 u1 = __float_as_uint(m.y) + 0x80u;
            const uint32 u2 = __float_as_uint(m.z) + 0x80u;
            const uint32 u3 = __float_as_uint(m.w) + 0x80u;
            uint2 hh;
            hh.x = (u0 >> 16) | (u1 & 0xFFFF0000u);
            hh.y = (u2 >> 16) | (u3 & 0xFFFF0000u);
            const uint32 ll = ((u0 >> 8) & 0xFFu)         | (((u1 >> 8) & 0xFFu) << 8) |
                              (((u2 >> 8) & 0xFFu) << 16) | (((u3 >> 8) & 0xFFu) << 24);
            hi2[off] = hh;
            lo1[off] = ll;
        }
    }
    pi_epilogue(acc, t, row0, s, vout, nsq_next);
}

// decode 4 elems: f32 = (hi<<16) | (lo<<8)
__device__ __forceinline__ float4 dec4f(uint32 h01, uint32 h23, uint32 l) {
    float4 f;
    f.x = __uint_as_float((h01 << 16)          | ((l & 0x000000FFu) << 8));
    f.y = __uint_as_float((h01 & 0xFFFF0000u)  | (l & 0x0000FF00u));
    f.z = __uint_as_float((h23 << 16)          | ((l >> 8) & 0x0000FF00u));
    f.w = __uint_as_float((h23 & 0xFFFF0000u)  | ((l >> 16) & 0x0000FF00u));
    return f;
}

// 3-byte GEMV, depth-3 row pipeline (4 static buffers), 32 elems/thread/row
__global__ __launch_bounds__(256, 3) void pi_gemv3_kernel(
        const uint4* __restrict__ hi4,   // row stride N/8 uint4
        const uint4* __restrict__ lo4,   // row stride N/16 uint4
        const float4* __restrict__ vin4,
        float* __restrict__ vout,
        const float* __restrict__ nsq_prev,
        float* __restrict__ nsq_next) {
    const int t = threadIdx.x;
    const int row0 = blockIdx.x * ROWS;
    const float s = rsqrtf(*nsq_prev);

    // vin: elems [16t,16t+16) and [16t+4096, 16t+4096+16)
    float4 v[8];
#pragma unroll
    for (int i = 0; i < 4; ++i) v[i] = vin4[4 * t + i];
#pragma unroll
    for (int i = 0; i < 4; ++i) v[4 + i] = vin4[4 * t + 1024 + i];

    uint4 h[4][4];
    uint4 l[4][2];
    float acc[ROWS];

#define LOADROW(r, b)                                                         \
    {                                                                         \
        const size_t hb = (size_t)(row0 + (r)) * (N / 8);                     \
        const size_t lb = (size_t)(row0 + (r)) * (N / 16);                    \
        h[(b)][0] = hi4[hb + 2 * t];                                          \
        h[(b)][1] = hi4[hb + 2 * t + 1];                                      \
        h[(b)][2] = hi4[hb + 2 * t + 512];                                    \
        h[(b)][3] = hi4[hb + 2 * t + 513];                                    \
        l[(b)][0] = lo4[lb + t];                                              \
        l[(b)][1] = lo4[lb + t + 256];                                        \
    }

#define COMPROW(r, b)                                                         \
    {                                                                         \
        float4 f;                                                             \
        float a = 0.0f;                                                       \
        f = dec4f(h[(b)][0].x, h[(b)][0].y, l[(b)][0].x);                     \
        a += f.x * v[0].x + f.y * v[0].y + f.z * v[0].z + f.w * v[0].w;       \
        f = dec4f(h[(b)][0].z, h[(b)][0].w, l[(b)][0].y);                     \
        a += f.x * v[1].x + f.y * v[1].y + f.z * v[1].z + f.w * v[1].w;       \
        f = dec4f(h[(b)][1].x, h[(b)][1].y, l[(b)][0].z);                     \
        a += f.x * v[2].x + f.y * v[2].y + f.z * v[2].z + f.w * v[2].w;       \
        f = dec4f(h[(b)][1].z, h[(b)][1].w, l[(b)][0].w);                     \
        a += f.x * v[3].x + f.y * v[3].y + f.z * v[3].z + f.w * v[3].w;       \
        f = dec4f(h[(b)][2].x, h[(b)][2].y, l[(b)][1].x);                     \
        a += f.x * v[4].x + f.y * v[4].y + f.z * v[4].z + f.w * v[4].w;       \
        f = dec4f(h[(b)][2].z, h[(b)][2].w, l[(b)][1].y);                     \
        a += f.x * v[5].x + f.y * v[5].y + f.z * v[5].z + f.w * v[5].w;       \
        f = dec4f(h[(b)][3].x, h[(b)][3].y, l[(b)][1].z);                     \
        a += f.x * v[6].x + f.y * v[6].y + f.z * v[6].z + f.w * v[6].w;       \
        f = dec4f(h[(b)][3].z, h[(b)][3].w, l[(b)][1].w);                     \
        a += f.x * v[7].x + f.y * v[7].y + f.z * v[7].z + f.w * v[7].w;       \
        acc[(r)] = a;                                                         \
    }

    LOADROW(0, 0)
    LOADROW(1, 1)
    LOADROW(2, 2)
    LOADROW(3, 3)
    COMPROW(0, 0)
    LOADROW(4, 0)
    COMPROW(1, 1)
    LOADROW(5, 1)
    COMPROW(2, 2)
    LOADROW(6, 2)
    COMPROW(3, 3)
    LOADROW(7, 3)
    COMPROW(4, 0)
    COMPROW(5, 1)
    COMPROW(6, 2)
    COMPROW(7, 3)

#undef LOADROW
#undef COMPROW

    pi_epilogue(acc, t, row0, s, vout, nsq_next);
}

__global__ void pi_scale_kernel(const float* __restrict__ vin,
                                const float* __restrict__ nsq,
                                float* __restrict__ out) {
    int i = blockIdx.x * blockDim.x + threadIdx.x;
    const float s = rsqrtf(*nsq);
    if (i < N) out[i] = vin[i] * s;
}

extern "C" void kernel_launch(void* const* d_in, const int* in_sizes, int n_in,
                              void* d_out, int out_size, void* d_ws, size_t ws_size,
                              hipStream_t stream) {
    const float* M = (const float*)d_in[0];
    float* out = (float*)d_out;

    const size_t HI_BYTES = (size_t)N * N * 2;   // 128 MiB
    const size_t LO_BYTES = (size_t)N * N;       //  64 MiB
    const size_t VEC_BYTES = (size_t)(2 * N + ITERS + 1) * sizeof(float);
    const bool use3 = (ws_size >= HI_BYTES + LO_BYTES + VEC_BYTES);

    char* ws = (char*)d_ws;
    float* bufA;
    float* bufB;
    float* nsq;
    uint32* hi = nullptr;
    uint32* lo = nullptr;
    if (use3) {
        hi   = (uint32*)ws;
        lo   = (uint32*)(ws + HI_BYTES);
        bufA = (float*)(ws + HI_BYTES + LO_BYTES);
        bufB = bufA + N;
        nsq  = bufB + N;
    } else {
        bufA = (float*)ws;
        bufB = bufA + N;
        nsq  = bufB + N;
    }

    pi_init_kernel<<<(N + 255) / 256, 256, 0, stream>>>(bufA, nsq);

    const float4* M4 = (const float4*)M;
    if (use3) {
        pi_gemv_convert_kernel<<<N / ROWS, 256, 0, stream>>>(
            M4, (const float4*)bufA, bufB, nsq, nsq + 1, (uint2*)hi, lo);
        for (int k = 2; k <= ITERS; ++k) {
            const float* vin = (k & 1) ? bufA : bufB;
            float* vout      = (k & 1) ? bufB : bufA;
            pi_gemv3_kernel<<<N / ROWS, 256, 0, stream>>>(
                (const uint4*)hi, (const uint4*)lo,
                (const float4*)vin, vout, nsq + (k - 1), nsq + k);
        }
    } else {
        for (int k = 1; k <= ITERS; ++k) {
            const float* vin = (k & 1) ? bufA : bufB;
            float* vout      = (k & 1) ? bufB : bufA;
            pi_gemv_kernel<<<N / ROWS, 256, 0, stream>>>(
                M4, (const float4*)vin, vout, nsq + (k - 1), nsq + k);
        }
    }
    pi_scale_kernel<<<(N + 255) / 256, 256, 0, stream>>>(bufA, nsq + ITERS, out);
}

// Round 4
// 1769.117 us; speedup vs baseline: 1.7920x; 1.7920x over previous
//
#include <hip/hip_runtime.h>

#define N 8192
#define ITERS 50
#define ROWS 8   // rows per gemv3 block

typedef unsigned int uint32;

// Packed 3-byte plane layout (one stream, all-16B accesses):
//   row = 8 tiles of 1024 elems; tile = 3 KB:
//     [0,1K):  hiA — lane l's uint4 at byte 16l = hi-halves of elems 16l..16l+7
//     [1K,2K): hiB — hi-halves of elems 16l+8..16l+15
//     [2K,3K): lo  — lane l's uint4 = low bytes (bits 15:8) of elems 16l..16l+15
//   row stride = 24 KB = 1536 uint4.  Element value bits = (hi<<16)|(lo<<8),
//   rounded-to-nearest at encode time (+0x80 before truncation).

__global__ void pi_init_kernel(float* __restrict__ bufA, float* __restrict__ nsq) {
    int i = blockIdx.x * blockDim.x + threadIdx.x;
    if (i < N) bufA[i] = 1.0f;
    if (i <= ITERS) nsq[i] = (i == 0) ? 1.0f : 0.0f;
}

// epilogue for ROWS-per-block gemv kernels
__device__ __forceinline__ void pi_epilogue(float (&acc)[ROWS], int t, int row0,
                                            float s, float* __restrict__ vout,
                                            float* __restrict__ nsq_next) {
#pragma unroll
    for (int r = 0; r < ROWS; ++r) {
        float a = acc[r];
        for (int off = 32; off > 0; off >>= 1) a += __shfl_down(a, off, 64);
        acc[r] = a;
    }
    __shared__ float part[4][ROWS];
    const int wave = t >> 6, lane = t & 63;
    if (lane == 0) {
#pragma unroll
        for (int r = 0; r < ROWS; ++r) part[wave][r] = acc[r];
    }
    __syncthreads();
    float sq = 0.0f;
    if (t < ROWS) {
        const float sum = part[0][t] + part[1][t] + part[2][t] + part[3][t];
        const float y = sum * s;
        vout[row0 + t] = y;
        sq = y * y;
    }
    if (wave == 0) {
        for (int off = 32; off > 0; off >>= 1) sq += __shfl_down(sq, off, 64);
        if (lane == 0) atomicAdd(nsq_next, sq);
    }
}

// fp32 GEMV (fallback for small ws)
__global__ __launch_bounds__(256) void pi_gemv_kernel(
        const float4* __restrict__ M4,
        const float4* __restrict__ vin4,
        float* __restrict__ vout,
        const float* __restrict__ nsq_prev,
        float* __restrict__ nsq_next) {
    const int t = threadIdx.x;
    const int row0 = blockIdx.x * ROWS;
    const float s = rsqrtf(*nsq_prev);
    constexpr int NV = N / 4;
    constexpr int CHUNKS = NV / 256;
    float acc[ROWS];
#pragma unroll
    for (int r = 0; r < ROWS; ++r) acc[r] = 0.0f;
    for (int c = 0; c < CHUNKS; ++c) {
        const int idx = c * 256 + t;
        const float4 vv = vin4[idx];
#pragma unroll
        for (int r = 0; r < ROWS; ++r) {
            const float4 m = M4[(size_t)(row0 + r) * NV + idx];
            acc[r] += m.x * vv.x + m.y * vv.y + m.z * vv.z + m.w * vv.w;
        }
    }
    pi_epilogue(acc, t, row0, s, vout, nsq_next);
}

// iter 1: GEMV fused with conversion into the packed plane. 1 row per block.
__global__ __launch_bounds__(256) void pi_convert_kernel(
        const float4* __restrict__ M4,
        const float4* __restrict__ vin4,
        float* __restrict__ vout,
        const float* __restrict__ nsq_prev,
        float* __restrict__ nsq_next,
        uint4* __restrict__ pk) {
    const int row = blockIdx.x;
    const int t = threadIdx.x, w = t >> 6, l = t & 63;
    const float s = rsqrtf(*nsq_prev);
    const size_t rf = (size_t)row * (N / 4);   // float4 row base
    const size_t rp = (size_t)row * 1536;      // uint4 packed row base
    float a = 0.0f;
#pragma unroll
    for (int half = 0; half < 2; ++half) {
        const int tile = w + 4 * half;
        float4 m[4];
#pragma unroll
        for (int j = 0; j < 4; ++j) m[j] = M4[rf + tile * 256 + 4 * l + j];
#pragma unroll
        for (int j = 0; j < 4; ++j) {
            const float4 vv = vin4[tile * 256 + 4 * l + j];
            a += m[j].x * vv.x + m[j].y * vv.y + m[j].z * vv.z + m[j].w * vv.w;
        }
        uint32 u[16];
#pragma unroll
        for (int j = 0; j < 4; ++j) {
            u[4 * j + 0] = __float_as_uint(m[j].x) + 0x80u;
            u[4 * j + 1] = __float_as_uint(m[j].y) + 0x80u;
            u[4 * j + 2] = __float_as_uint(m[j].z) + 0x80u;
            u[4 * j + 3] = __float_as_uint(m[j].w) + 0x80u;
        }
        uint4 hA, hB, lu;
        hA.x = (u[0] >> 16)  | (u[1] & 0xFFFF0000u);
        hA.y = (u[2] >> 16)  | (u[3] & 0xFFFF0000u);
        hA.z = (u[4] >> 16)  | (u[5] & 0xFFFF0000u);
        hA.w = (u[6] >> 16)  | (u[7] & 0xFFFF0000u);
        hB.x = (u[8] >> 16)  | (u[9] & 0xFFFF0000u);
        hB.y = (u[10] >> 16) | (u[11] & 0xFFFF0000u);
        hB.z = (u[12] >> 16) | (u[13] & 0xFFFF0000u);
        hB.w = (u[14] >> 16) | (u[15] & 0xFFFF0000u);
        lu.x = ((u[0] >> 8) & 0xFFu)  | (((u[1] >> 8) & 0xFFu) << 8)  |
               (((u[2] >> 8) & 0xFFu) << 16)  | (((u[3] >> 8) & 0xFFu) << 24);
        lu.y = ((u[4] >> 8) & 0xFFu)  | (((u[5] >> 8) & 0xFFu) << 8)  |
               (((u[6] >> 8) & 0xFFu) << 16)  | (((u[7] >> 8) & 0xFFu) << 24);
        lu.z = ((u[8] >> 8) & 0xFFu)  | (((u[9] >> 8) & 0xFFu) << 8)  |
               (((u[10] >> 8) & 0xFFu) << 16) | (((u[11] >> 8) & 0xFFu) << 24);
        lu.w = ((u[12] >> 8) & 0xFFu) | (((u[13] >> 8) & 0xFFu) << 8) |
               (((u[14] >> 8) & 0xFFu) << 16) | (((u[15] >> 8) & 0xFFu) << 24);
        const size_t tb = rp + (size_t)tile * 192;
        pk[tb + l]       = hA;
        pk[tb + 64 + l]  = hB;
        pk[tb + 128 + l] = lu;
    }
    // block reduction (one row)
    for (int off = 32; off > 0; off >>= 1) a += __shfl_down(a, off, 64);
    __shared__ float part[4];
    if (l == 0) part[w] = a;
    __syncthreads();
    if (t == 0) {
        const float sum = part[0] + part[1] + part[2] + part[3];
        const float y = sum * s;
        vout[row] = y;
        atomicAdd(nsq_next, y * y);
    }
}

// decode 4 elems: f32 = (hi<<16) | (lo<<8)
__device__ __forceinline__ float4 dec4f(uint32 h01, uint32 h23, uint32 l) {
    float4 f;
    f.x = __uint_as_float((h01 << 16)         | ((l & 0x000000FFu) << 8));
    f.y = __uint_as_float((h01 & 0xFFFF0000u) | (l & 0x0000FF00u));
    f.z = __uint_as_float((h23 << 16)         | ((l >> 8) & 0x0000FF00u));
    f.w = __uint_as_float((h23 & 0xFFFF0000u) | ((l >> 16) & 0x0000FF00u));
    return f;
}

// 3-byte GEMV on the packed plane: every load is a 16B uint4, one stream.
__global__ __launch_bounds__(256) void pi_gemv3_kernel(
        const uint4* __restrict__ pk,
        const float4* __restrict__ vin4,
        float* __restrict__ vout,
        const float* __restrict__ nsq_prev,
        float* __restrict__ nsq_next) {
    const int t = threadIdx.x, w = t >> 6, l = t & 63;
    const int row0 = blockIdx.x * ROWS;
    const float s = rsqrtf(*nsq_prev);

    // this thread's v slices: tiles w and w+4, elems 16l..16l+15 of each
    float4 va[4], vb[4];
#pragma unroll
    for (int j = 0; j < 4; ++j) va[j] = vin4[w * 256 + 4 * l + j];
#pragma unroll
    for (int j = 0; j < 4; ++j) vb[j] = vin4[(w + 4) * 256 + 4 * l + j];

    float acc[ROWS];
#pragma unroll
    for (int r = 0; r < ROWS; ++r) {
        const size_t b = (size_t)(row0 + r) * 1536 + (size_t)w * 192 + l;
        const uint4 hA  = pk[b];
        const uint4 hB  = pk[b + 64];
        const uint4 lu  = pk[b + 128];
        const uint4 hA2 = pk[b + 768];
        const uint4 hB2 = pk[b + 832];
        const uint4 lu2 = pk[b + 896];
        float4 f;
        float a = 0.0f;
        f = dec4f(hA.x, hA.y, lu.x);
        a += f.x * va[0].x + f.y * va[0].y + f.z * va[0].z + f.w * va[0].w;
        f = dec4f(hA.z, hA.w, lu.y);
        a += f.x * va[1].x + f.y * va[1].y + f.z * va[1].z + f.w * va[1].w;
        f = dec4f(hB.x, hB.y, lu.z);
        a += f.x * va[2].x + f.y * va[2].y + f.z * va[2].z + f.w * va[2].w;
        f = dec4f(hB.z, hB.w, lu.w);
        a += f.x * va[3].x + f.y * va[3].y + f.z * va[3].z + f.w * va[3].w;
        f = dec4f(hA2.x, hA2.y, lu2.x);
        a += f.x * vb[0].x + f.y * vb[0].y + f.z * vb[0].z + f.w * vb[0].w;
        f = dec4f(hA2.z, hA2.w, lu2.y);
        a += f.x * vb[1].x + f.y * vb[1].y + f.z * vb[1].z + f.w * vb[1].w;
        f = dec4f(hB2.x, hB2.y, lu2.z);
        a += f.x * vb[2].x + f.y * vb[2].y + f.z * vb[2].z + f.w * vb[2].w;
        f = dec4f(hB2.z, hB2.w, lu2.w);
        a += f.x * vb[3].x + f.y * vb[3].y + f.z * vb[3].z + f.w * vb[3].w;
        acc[r] = a;
    }
    pi_epilogue(acc, t, row0, s, vout, nsq_next);
}

__global__ void pi_scale_kernel(const float* __restrict__ vin,
                                const float* __restrict__ nsq,
                                float* __restrict__ out) {
    int i = blockIdx.x * blockDim.x + threadIdx.x;
    const float s = rsqrtf(*nsq);
    if (i < N) out[i] = vin[i] * s;
}

extern "C" void kernel_launch(void* const* d_in, const int* in_sizes, int n_in,
                              void* d_out, int out_size, void* d_ws, size_t ws_size,
                              hipStream_t stream) {
    const float* M = (const float*)d_in[0];
    float* out = (float*)d_out;

    const size_t PK_BYTES = (size_t)N * N * 3;   // 192 MiB packed plane
    const size_t VEC_BYTES = (size_t)(2 * N + ITERS + 1) * sizeof(float);
    const bool use3 = (ws_size >= PK_BYTES + VEC_BYTES);

    char* ws = (char*)d_ws;
    float* bufA;
    float* bufB;
    float* nsq;
    uint4* pk = nullptr;
    if (use3) {
        pk   = (uint4*)ws;
        bufA = (float*)(ws + PK_BYTES);
        bufB = bufA + N;
        nsq  = bufB + N;
    } else {
        bufA = (float*)ws;
        bufB = bufA + N;
        nsq  = bufB + N;
    }

    pi_init_kernel<<<(N + 255) / 256, 256, 0, stream>>>(bufA, nsq);

    const float4* M4 = (const float4*)M;
    if (use3) {
        pi_convert_kernel<<<N, 256, 0, stream>>>(
            M4, (const float4*)bufA, bufB, nsq, nsq + 1, pk);
        for (int k = 2; k <= ITERS; ++k) {
            const float* vin = (k & 1) ? bufA : bufB;
            float* vout      = (k & 1) ? bufB : bufA;
            pi_gemv3_kernel<<<N / ROWS, 256, 0, stream>>>(
                pk, (const float4*)vin, vout, nsq + (k - 1), nsq + k);
        }
    } else {
        for (int k = 1; k <= ITERS; ++k) {
            const float* vin = (k & 1) ? bufA : bufB;
            float* vout      = (k & 1) ? bufB : bufA;
            pi_gemv_kernel<<<N / ROWS, 256, 0, stream>>>(
                M4, (const float4*)vin, vout, nsq + (k - 1), nsq + k);
        }
    }
    pi_scale_kernel<<<(N + 255) / 256, 256, 0, stream>>>(bufA, nsq + ITERS, out);
}

// Round 5
// 1572.157 us; speedup vs baseline: 2.0165x; 1.1253x over previous
//
#include <hip/hip_runtime.h>
#include <hip/hip_fp16.h>

#define N 8192
#define ITERS 50
#define ROWS 8   // rows per gemv block

typedef unsigned int uint32;

// ws layout: [fp16 plane 128MiB][bufA N][bufB N][nsq ITERS+1]
// fp16 plane: row-major __half, RTNE from fp32. Hot-loop access: uint4 loads
// (8 halfs/lane, 64 lanes = 1KB contiguous per instruction — the round-4
// proven single-stream pattern).

__global__ void pi_init_kernel(float* __restrict__ bufA, float* __restrict__ nsq) {
    int i = blockIdx.x * blockDim.x + threadIdx.x;
    if (i < N) bufA[i] = 1.0f;
    if (i <= ITERS) nsq[i] = (i == 0) ? 1.0f : 0.0f;
}

// epilogue for ROWS-per-block gemv kernels: per-row wave reduce -> LDS ->
// write vout, accumulate sum(vout^2) into nsq_next
__device__ __forceinline__ void pi_epilogue(float (&acc)[ROWS], int t, int row0,
                                            float s, float* __restrict__ vout,
                                            float* __restrict__ nsq_next) {
#pragma unroll
    for (int r = 0; r < ROWS; ++r) {
        float a = acc[r];
        for (int off = 32; off > 0; off >>= 1) a += __shfl_down(a, off, 64);
        acc[r] = a;
    }
    __shared__ float part[4][ROWS];
    const int wave = t >> 6, lane = t & 63;
    if (lane == 0) {
#pragma unroll
        for (int r = 0; r < ROWS; ++r) part[wave][r] = acc[r];
    }
    __syncthreads();
    float sq = 0.0f;
    if (t < ROWS) {
        const float sum = part[0][t] + part[1][t] + part[2][t] + part[3][t];
        const float y = sum * s;
        vout[row0 + t] = y;
        sq = y * y;
    }
    if (wave == 0) {
        for (int off = 32; off > 0; off >>= 1) sq += __shfl_down(sq, off, 64);
        if (lane == 0) atomicAdd(nsq_next, sq);
    }
}

// fp32 GEMV (fallback for small ws)
__global__ __launch_bounds__(256) void pi_gemv_kernel(
        const float4* __restrict__ M4,
        const float4* __restrict__ vin4,
        float* __restrict__ vout,
        const float* __restrict__ nsq_prev,
        float* __restrict__ nsq_next) {
    const int t = threadIdx.x;
    const int row0 = blockIdx.x * ROWS;
    const float s = rsqrtf(*nsq_prev);
    constexpr int NV = N / 4;
    constexpr int CHUNKS = NV / 256;
    float acc[ROWS];
#pragma unroll
    for (int r = 0; r < ROWS; ++r) acc[r] = 0.0f;
    for (int c = 0; c < CHUNKS; ++c) {
        const int idx = c * 256 + t;
        const float4 vv = vin4[idx];
#pragma unroll
        for (int r = 0; r < ROWS; ++r) {
            const float4 m = M4[(size_t)(row0 + r) * NV + idx];
            acc[r] += m.x * vv.x + m.y * vv.y + m.z * vv.z + m.w * vv.w;
        }
    }
    pi_epilogue(acc, t, row0, s, vout, nsq_next);
}

__device__ __forceinline__ uint32 pack2h(float x, float y) {
    __half2 p = __float22half2_rn(make_float2(x, y));
    return *reinterpret_cast<uint32*>(&p);
}

// iter 1: fp32 GEMV fused with fp16 conversion. One row per block.
__global__ __launch_bounds__(256) void pi_convert_kernel(
        const float4* __restrict__ M4,
        const float4* __restrict__ vin4,
        float* __restrict__ vout,
        const float* __restrict__ nsq_prev,
        float* __restrict__ nsq_next,
        uint4* __restrict__ h4) {
    const int row = blockIdx.x;
    const int t = threadIdx.x, w = t >> 6, l = t & 63;
    const float s = rsqrtf(*nsq_prev);
    const size_t rf = (size_t)row * (N / 4);   // float4 row base
    const size_t rh = (size_t)row * (N / 8);   // uint4  row base (1024)
    float a = 0.0f;
#pragma unroll
    for (int half = 0; half < 2; ++half) {
        const int tile = w + 4 * half;         // 0..7, 1024 elems each
        float4 m[4];
#pragma unroll
        for (int j = 0; j < 4; ++j) m[j] = M4[rf + tile * 256 + 4 * l + j];
#pragma unroll
        for (int j = 0; j < 4; ++j) {
            const float4 vv = vin4[tile * 256 + 4 * l + j];
            a += m[j].x * vv.x + m[j].y * vv.y + m[j].z * vv.z + m[j].w * vv.w;
        }
        uint4 o0, o1;
        o0.x = pack2h(m[0].x, m[0].y);
        o0.y = pack2h(m[0].z, m[0].w);
        o0.z = pack2h(m[1].x, m[1].y);
        o0.w = pack2h(m[1].z, m[1].w);
        o1.x = pack2h(m[2].x, m[2].y);
        o1.y = pack2h(m[2].z, m[2].w);
        o1.z = pack2h(m[3].x, m[3].y);
        o1.w = pack2h(m[3].z, m[3].w);
        h4[rh + tile * 128 + 2 * l]     = o0;
        h4[rh + tile * 128 + 2 * l + 1] = o1;
    }
    for (int off = 32; off > 0; off >>= 1) a += __shfl_down(a, off, 64);
    __shared__ float part[4];
    if (l == 0) part[w] = a;
    __syncthreads();
    if (t == 0) {
        const float sum = part[0] + part[1] + part[2] + part[3];
        const float y = sum * s;
        vout[row] = y;
        atomicAdd(nsq_next, y * y);
    }
}

__device__ __forceinline__ float2 h2f(uint32 u) {
    __half2 h = *reinterpret_cast<__half2*>(&u);
    return __half22float2(h);
}

// fp16 GEMV: all loads 16B uint4, one sequential stream per row set.
__global__ __launch_bounds__(256) void pi_gemv2h_kernel(
        const uint4* __restrict__ h4,    // row stride N/8 = 1024 uint4
        const float4* __restrict__ vin4,
        float* __restrict__ vout,
        const float* __restrict__ nsq_prev,
        float* __restrict__ nsq_next) {
    const int t = threadIdx.x;
    const int row0 = blockIdx.x * ROWS;
    const float s = rsqrtf(*nsq_prev);
    float acc[ROWS];
#pragma unroll
    for (int r = 0; r < ROWS; ++r) acc[r] = 0.0f;
#pragma unroll
    for (int c = 0; c < 4; ++c) {
        const int idx = c * 256 + t;           // uint4 index in row, 0..1023
        const float4 va = vin4[2 * idx];       // elems 8*idx .. 8*idx+3
        const float4 vb = vin4[2 * idx + 1];   // elems 8*idx+4 .. 8*idx+7
#pragma unroll
        for (int r = 0; r < ROWS; ++r) {
            const uint4 h = h4[(size_t)(row0 + r) * 1024 + idx];
            const float2 f0 = h2f(h.x);
            const float2 f1 = h2f(h.y);
            const float2 f2 = h2f(h.z);
            const float2 f3 = h2f(h.w);
            acc[r] += f0.x * va.x + f0.y * va.y + f1.x * va.z + f1.y * va.w +
                      f2.x * vb.x + f2.y * vb.y + f3.x * vb.z + f3.y * vb.w;
        }
    }
    pi_epilogue(acc, t, row0, s, vout, nsq_next);
}

__global__ void pi_scale_kernel(const float* __restrict__ vin,
                                const float* __restrict__ nsq,
                                float* __restrict__ out) {
    int i = blockIdx.x * blockDim.x + threadIdx.x;
    const float s = rsqrtf(*nsq);
    if (i < N) out[i] = vin[i] * s;
}

extern "C" void kernel_launch(void* const* d_in, const int* in_sizes, int n_in,
                              void* d_out, int out_size, void* d_ws, size_t ws_size,
                              hipStream_t stream) {
    const float* M = (const float*)d_in[0];
    float* out = (float*)d_out;

    const size_t H_BYTES = (size_t)N * N * 2;   // 128 MiB fp16 plane
    const size_t VEC_BYTES = (size_t)(2 * N + ITERS + 1) * sizeof(float);
    const bool use2 = (ws_size >= H_BYTES + VEC_BYTES);

    char* ws = (char*)d_ws;
    float* bufA;
    float* bufB;
    float* nsq;
    uint4* h4 = nullptr;
    if (use2) {
        h4   = (uint4*)ws;
        bufA = (float*)(ws + H_BYTES);
        bufB = bufA + N;
        nsq  = bufB + N;
    } else {
        bufA = (float*)ws;
        bufB = bufA + N;
        nsq  = bufB + N;
    }

    pi_init_kernel<<<(N + 255) / 256, 256, 0, stream>>>(bufA, nsq);

    const float4* M4 = (const float4*)M;
    if (use2) {
        pi_convert_kernel<<<N, 256, 0, stream>>>(
            M4, (const float4*)bufA, bufB, nsq, nsq + 1, h4);
        for (int k = 2; k <= ITERS; ++k) {
            const float* vin = (k & 1) ? bufA : bufB;
            float* vout      = (k & 1) ? bufB : bufA;
            pi_gemv2h_kernel<<<N / ROWS, 256, 0, stream>>>(
                h4, (const float4*)vin, vout, nsq + (k - 1), nsq + k);
        }
    } else {
        for (int k = 1; k <= ITERS; ++k) {
            const float* vin = (k & 1) ? bufA : bufB;
            float* vout      = (k & 1) ? bufB : bufA;
            pi_gemv_kernel<<<N / ROWS, 256, 0, stream>>>(
                M4, (const float4*)vin, vout, nsq + (k - 1), nsq + k);
        }
    }
    pi_scale_kernel<<<(N + 255) / 256, 256, 0, stream>>>(bufA, nsq + ITERS, out);
}